// Round 2
// baseline (43.479 us; speedup 1.0000x reference)
//
#include <hip/hip_runtime.h>

// out[b,u] = tanh( exp( max_i x[b,i]*W[i,u] ) - 1 + bias[u] )
// exp monotonic -> max commutes with exp -> max-times "GEMM" + transcendental epilogue.
//
// Dataflow (no LDS, no barriers):
//   wave owns 8 batch rows x 64 units (lane = unit).
//   x[row][k]   : wave-uniform -> s_load (scalar cache), zero vector cost
//   W[k][u]     : per-lane coalesced global load, L1/L2 resident (W = 1 MB)
//   acc via fmaxf(fmaxf(acc,p0),p1) pairs -> v_max3_f32 (1.5 VALU ops/product)

#define BATCH 2048
#define INDIM 512
#define UNITS 512

#define M 8      // rows per wave
#define KU 8     // k-unroll per block (also W prefetch distance)

__global__ __launch_bounds__(256) void maxexp_kernel(
    const float* __restrict__ x,     // [BATCH][INDIM]
    const float* __restrict__ W,     // [INDIM][UNITS]
    const float* __restrict__ bias,  // [UNITS]
    float* __restrict__ out)         // [BATCH][UNITS]
{
    const int lane = threadIdx.x & 63;
    // force wave index uniform so x addressing scalarizes to s_load
    const int wv   = __builtin_amdgcn_readfirstlane(threadIdx.x >> 6);
    const int u    = blockIdx.x * 64 + lane;              // unit column (per-lane)
    const int b0   = blockIdx.y * 32 + wv * M;            // first batch row (uniform)

    const float* xrow = x + (size_t)b0 * INDIM;           // uniform base
    const float* wcol = W + u;                            // per-lane base

    float acc[M];
#pragma unroll
    for (int m = 0; m < M; ++m) acc[m] = -3.4e38f;

    float wA[KU], wB[KU];

#define LOADW(dst, kbi)                                               \
    {                                                                 \
        const float* wp = wcol + (size_t)(kbi) * KU * UNITS;          \
        _Pragma("unroll")                                             \
        for (int j = 0; j < KU; ++j) (dst)[j] = wp[(size_t)j * UNITS];\
    }

#define COMPUTE(wreg, kbi)                                            \
    {                                                                 \
        const float* xr = xrow + (kbi) * KU;                          \
        _Pragma("unroll")                                             \
        for (int m = 0; m < M; ++m) {                                 \
            const float4 a  = *reinterpret_cast<const float4*>(xr + m * INDIM);     \
            const float4 b2 = *reinterpret_cast<const float4*>(xr + m * INDIM + 4); \
            float p0 = a.x  * (wreg)[0], p1 = a.y  * (wreg)[1];       \
            acc[m] = fmaxf(fmaxf(acc[m], p0), p1);                    \
            float p2 = a.z  * (wreg)[2], p3 = a.w  * (wreg)[3];       \
            acc[m] = fmaxf(fmaxf(acc[m], p2), p3);                    \
            float p4 = b2.x * (wreg)[4], p5 = b2.y * (wreg)[5];       \
            acc[m] = fmaxf(fmaxf(acc[m], p4), p5);                    \
            float p6 = b2.z * (wreg)[6], p7 = b2.w * (wreg)[7];       \
            acc[m] = fmaxf(fmaxf(acc[m], p6), p7);                    \
        }                                                             \
    }

    const int NKB = INDIM / KU;   // 64 k-blocks
    LOADW(wA, 0);
    for (int kb = 0; kb < NKB; kb += 2) {
        LOADW(wB, kb + 1);        // prefetch next block (always valid: kb+1 <= 63)
        COMPUTE(wA, kb);
        if (kb + 2 < NKB) LOADW(wA, kb + 2);
        COMPUTE(wB, kb + 1);
    }

    // epilogue: tanh(exp(m) - 1 + bias)
    const float bv = bias[u];
#pragma unroll
    for (int m = 0; m < M; ++m) {
        const float p = __expf(acc[m]) - 1.0f + bv;
        const float e = __expf(2.0f * p);
        out[(size_t)(b0 + m) * UNITS + u] = 1.0f - 2.0f / (e + 1.0f);
    }
#undef LOADW
#undef COMPUTE
}

extern "C" void kernel_launch(void* const* d_in, const int* in_sizes, int n_in,
                              void* d_out, int out_size, void* d_ws, size_t ws_size,
                              hipStream_t stream) {
    const float* x    = (const float*)d_in[0];
    const float* W    = (const float*)d_in[1];
    const float* bias = (const float*)d_in[2];
    float* out = (float*)d_out;

    dim3 grid(UNITS / 64, BATCH / 32);   // (8, 64) = 512 blocks, 2048 waves
    dim3 block(256);                     // 4 waves/block
    maxexp_kernel<<<grid, block, 0, stream>>>(x, W, bias, out);
}